// Round 1
// baseline (2644.499 us; speedup 1.0000x reference)
//
#include <hip/hip_runtime.h>
#include <math.h>

// Problem constants (fixed by reference)
constexpr int B  = 2;
constexpr int N  = 4096;
constexpr int D  = 512;
constexpr int H  = 8;
constexpr int DK = 64;           // D / H
constexpr int M  = B * N;        // 8192 rows
constexpr float SCALE = 0.125f;  // 1/sqrt(64)
constexpr float LN_EPS = 1e-5f;

#define DEV static __device__ __forceinline__

DEV float wave_red_max(float x) {
#pragma unroll
  for (int o = 32; o > 0; o >>= 1) x = fmaxf(x, __shfl_xor(x, o));
  return x;
}
DEV float wave_red_sum(float x) {
#pragma unroll
  for (int o = 32; o > 0; o >>= 1) x += __shfl_xor(x, o);
  return x;
}

// ---------------------------------------------------------------------------
// K1: P = X @ W^T  (X: [M,D] fp32, W: [D,D] row-major, out head-split
//     P[b][h][n][dk], b=row/N). Col tile (64) == exactly one head.
// grid: (M/64, H), block 256
// ---------------------------------------------------------------------------
__global__ __launch_bounds__(256) void proj_kernel(
    const float* __restrict__ X, const float* __restrict__ W,
    float* __restrict__ P) {
  __shared__ float As[64][68];  // [k][row]
  __shared__ float Bs[64][68];  // [k][col]
  const int tid  = threadIdx.x;
  const int row0 = blockIdx.x * 64;
  const int h    = blockIdx.y;
  const int col0 = h * 64;
  const int lr = tid >> 4;     // 0..15
  const int lv = tid & 15;     // float4 index within 64 floats
  const int tr = (tid & 15) * 4;
  const int tc = (tid >> 4) * 4;
  float acc[4][4] = {};

  for (int k0 = 0; k0 < D; k0 += 64) {
#pragma unroll
    for (int i = 0; i < 4; ++i) {
      const int r = lr + i * 16;
      float4 a = *reinterpret_cast<const float4*>(&X[(size_t)(row0 + r) * D + k0 + lv * 4]);
      As[lv * 4 + 0][r] = a.x; As[lv * 4 + 1][r] = a.y;
      As[lv * 4 + 2][r] = a.z; As[lv * 4 + 3][r] = a.w;
      float4 w = *reinterpret_cast<const float4*>(&W[(size_t)(col0 + r) * D + k0 + lv * 4]);
      Bs[lv * 4 + 0][r] = w.x; Bs[lv * 4 + 1][r] = w.y;
      Bs[lv * 4 + 2][r] = w.z; Bs[lv * 4 + 3][r] = w.w;
    }
    __syncthreads();
#pragma unroll
    for (int kk = 0; kk < 64; ++kk) {
      float4 a4 = *reinterpret_cast<const float4*>(&As[kk][tr]);
      float4 b4 = *reinterpret_cast<const float4*>(&Bs[kk][tc]);
      float av[4] = {a4.x, a4.y, a4.z, a4.w};
      float bv[4] = {b4.x, b4.y, b4.z, b4.w};
#pragma unroll
      for (int i = 0; i < 4; ++i)
#pragma unroll
        for (int j = 0; j < 4; ++j) acc[i][j] = fmaf(av[i], bv[j], acc[i][j]);
    }
    __syncthreads();
  }

  const int b  = row0 / N;
  const int n0 = row0 % N;
  float* Pb = P + (size_t)(b * H + h) * N * DK;
#pragma unroll
  for (int i = 0; i < 4; ++i) {
    float4 o = make_float4(acc[i][0], acc[i][1], acc[i][2], acc[i][3]);
    *reinterpret_cast<float4*>(&Pb[(size_t)(n0 + tr + i) * DK + tc]) = o;
  }
}

// ---------------------------------------------------------------------------
// K2: raw scores = SCALE * KP @ QP^T per (b,h).  scores[i][j] = kp[i,:].qp[j,:]
// grid: (N/64, N/64, B*H), block 256. Writes into attn region of d_out.
// ---------------------------------------------------------------------------
__global__ __launch_bounds__(256) void scores_kernel(
    const float* __restrict__ KP, const float* __restrict__ QP,
    float* __restrict__ ATT) {
  __shared__ float Ks[64][68];  // [d][i]
  __shared__ float Qs[64][68];  // [d][j]
  const int tid = threadIdx.x;
  const int i0  = blockIdx.x * 64;
  const int j0  = blockIdx.y * 64;
  const int bh  = blockIdx.z;
  const float* Kb = KP + (size_t)bh * N * DK;
  const float* Qb = QP + (size_t)bh * N * DK;
  const int lr = tid >> 4, lv = tid & 15;
  const int ti = (tid & 15) * 4, tj = (tid >> 4) * 4;

#pragma unroll
  for (int ii = 0; ii < 4; ++ii) {
    const int r = lr + ii * 16;
    float4 a = *reinterpret_cast<const float4*>(&Kb[(size_t)(i0 + r) * DK + lv * 4]);
    Ks[lv * 4 + 0][r] = a.x; Ks[lv * 4 + 1][r] = a.y;
    Ks[lv * 4 + 2][r] = a.z; Ks[lv * 4 + 3][r] = a.w;
    float4 q = *reinterpret_cast<const float4*>(&Qb[(size_t)(j0 + r) * DK + lv * 4]);
    Qs[lv * 4 + 0][r] = q.x; Qs[lv * 4 + 1][r] = q.y;
    Qs[lv * 4 + 2][r] = q.z; Qs[lv * 4 + 3][r] = q.w;
  }
  __syncthreads();

  float acc[4][4] = {};
#pragma unroll
  for (int d = 0; d < 64; ++d) {
    float4 a4 = *reinterpret_cast<const float4*>(&Ks[d][ti]);
    float4 b4 = *reinterpret_cast<const float4*>(&Qs[d][tj]);
    float av[4] = {a4.x, a4.y, a4.z, a4.w};
    float bv[4] = {b4.x, b4.y, b4.z, b4.w};
#pragma unroll
    for (int i = 0; i < 4; ++i)
#pragma unroll
      for (int j = 0; j < 4; ++j) acc[i][j] = fmaf(av[i], bv[j], acc[i][j]);
  }

  float* Ab = ATT + ((size_t)bh * N + i0) * N + j0;
#pragma unroll
  for (int i = 0; i < 4; ++i) {
    float4 o = make_float4(acc[i][0] * SCALE, acc[i][1] * SCALE,
                           acc[i][2] * SCALE, acc[i][3] * SCALE);
    *reinterpret_cast<float4*>(&Ab[(size_t)(ti + i) * N + tj]) = o;
  }
}

// ---------------------------------------------------------------------------
// K3: in-place row softmax over attn rows (length N=4096).
// grid: (B*H*N), block 256; each thread holds 16 values in registers.
// ---------------------------------------------------------------------------
__global__ __launch_bounds__(256) void softmax_kernel(float* __restrict__ ATT) {
  __shared__ float red[4];
  const size_t row = blockIdx.x;
  float* p = ATT + row * (size_t)N;
  const int tid = threadIdx.x;

  float4 v[4];
  float mx = -1e30f;
#pragma unroll
  for (int c = 0; c < 4; ++c) {
    v[c] = *reinterpret_cast<const float4*>(&p[(size_t)(tid + c * 256) * 4]);
    mx = fmaxf(mx, fmaxf(fmaxf(v[c].x, v[c].y), fmaxf(v[c].z, v[c].w)));
  }
  mx = wave_red_max(mx);
  if ((tid & 63) == 0) red[tid >> 6] = mx;
  __syncthreads();
  mx = fmaxf(fmaxf(red[0], red[1]), fmaxf(red[2], red[3]));
  __syncthreads();

  float s = 0.f;
#pragma unroll
  for (int c = 0; c < 4; ++c) {
    v[c].x = __expf(v[c].x - mx); v[c].y = __expf(v[c].y - mx);
    v[c].z = __expf(v[c].z - mx); v[c].w = __expf(v[c].w - mx);
    s += v[c].x + v[c].y + v[c].z + v[c].w;
  }
  s = wave_red_sum(s);
  if ((tid & 63) == 0) red[tid >> 6] = s;
  __syncthreads();
  s = red[0] + red[1] + red[2] + red[3];
  const float inv = 1.0f / s;

#pragma unroll
  for (int c = 0; c < 4; ++c) {
    float4 o = make_float4(v[c].x * inv, v[c].y * inv, v[c].z * inv, v[c].w * inv);
    *reinterpret_cast<float4*>(&p[(size_t)(tid + c * 256) * 4]) = o;
  }
}

// ---------------------------------------------------------------------------
// K4: feat = attn @ VP per (b,h).  feat[i][d] = sum_j attn[i][j] vp[j][d]
// grid: (N/64, B*H), block 256.
// ---------------------------------------------------------------------------
__global__ __launch_bounds__(256) void pv_kernel(
    const float* __restrict__ ATT, const float* __restrict__ VP,
    float* __restrict__ FEAT) {
  __shared__ float As[64][68];  // [j][i]  (attn transposed)
  __shared__ float Vs[64][68];  // [j][d]
  const int tid = threadIdx.x;
  const int i0  = blockIdx.x * 64;
  const int bh  = blockIdx.y;
  const float* Ab = ATT + ((size_t)bh * N + i0) * N;
  const float* Vb = VP + (size_t)bh * N * DK;
  const int lr = tid >> 4, lv = tid & 15;
  const int ti = (tid & 15) * 4, td = (tid >> 4) * 4;
  float acc[4][4] = {};

  for (int j0 = 0; j0 < N; j0 += 64) {
#pragma unroll
    for (int ii = 0; ii < 4; ++ii) {
      const int r = lr + ii * 16;
      float4 a = *reinterpret_cast<const float4*>(&Ab[(size_t)r * N + j0 + lv * 4]);
      As[lv * 4 + 0][r] = a.x; As[lv * 4 + 1][r] = a.y;
      As[lv * 4 + 2][r] = a.z; As[lv * 4 + 3][r] = a.w;
      float4 vv = *reinterpret_cast<const float4*>(&Vb[(size_t)(j0 + r) * DK + lv * 4]);
      *reinterpret_cast<float4*>(&Vs[r][lv * 4]) = vv;
    }
    __syncthreads();
#pragma unroll
    for (int jj = 0; jj < 64; ++jj) {
      float4 a4 = *reinterpret_cast<const float4*>(&As[jj][ti]);
      float4 b4 = *reinterpret_cast<const float4*>(&Vs[jj][td]);
      float av[4] = {a4.x, a4.y, a4.z, a4.w};
      float bv[4] = {b4.x, b4.y, b4.z, b4.w};
#pragma unroll
      for (int i = 0; i < 4; ++i)
#pragma unroll
        for (int j = 0; j < 4; ++j) acc[i][j] = fmaf(av[i], bv[j], acc[i][j]);
    }
    __syncthreads();
  }

  float* Fb = FEAT + ((size_t)bh * N + i0) * DK;
#pragma unroll
  for (int i = 0; i < 4; ++i) {
    float4 o = make_float4(acc[i][0], acc[i][1], acc[i][2], acc[i][3]);
    *reinterpret_cast<float4*>(&Fb[(size_t)(ti + i) * DK + td]) = o;
  }
}

// ---------------------------------------------------------------------------
// K5: x = feat_headmerge @ Wfc^T + q    (feat head-split [B,H,N,DK])
// grid: (M/64, D/64), block 256. Output xb [M][D].
// ---------------------------------------------------------------------------
__global__ __launch_bounds__(256) void fc_kernel(
    const float* __restrict__ FEAT, const float* __restrict__ WFC,
    const float* __restrict__ Q, float* __restrict__ XB) {
  __shared__ float As[64][68];  // [k][row]
  __shared__ float Bs[64][68];  // [k][col]
  const int tid  = threadIdx.x;
  const int row0 = blockIdx.x * 64;
  const int col0 = blockIdx.y * 64;
  const int b  = row0 / N;
  const int n0 = row0 % N;
  const int lr = tid >> 4, lv = tid & 15;
  const int tr = (tid & 15) * 4, tc = (tid >> 4) * 4;
  float acc[4][4] = {};

  for (int k0 = 0; k0 < D; k0 += 64) {
    const int hk = k0 / 64;
    const float* Fb = FEAT + ((size_t)(b * H + hk) * N + n0) * DK;
#pragma unroll
    for (int i = 0; i < 4; ++i) {
      const int r = lr + i * 16;
      float4 a = *reinterpret_cast<const float4*>(&Fb[(size_t)r * DK + lv * 4]);
      As[lv * 4 + 0][r] = a.x; As[lv * 4 + 1][r] = a.y;
      As[lv * 4 + 2][r] = a.z; As[lv * 4 + 3][r] = a.w;
      float4 w = *reinterpret_cast<const float4*>(&WFC[(size_t)(col0 + r) * D + k0 + lv * 4]);
      Bs[lv * 4 + 0][r] = w.x; Bs[lv * 4 + 1][r] = w.y;
      Bs[lv * 4 + 2][r] = w.z; Bs[lv * 4 + 3][r] = w.w;
    }
    __syncthreads();
#pragma unroll
    for (int kk = 0; kk < 64; ++kk) {
      float4 a4 = *reinterpret_cast<const float4*>(&As[kk][tr]);
      float4 b4 = *reinterpret_cast<const float4*>(&Bs[kk][tc]);
      float av[4] = {a4.x, a4.y, a4.z, a4.w};
      float bv[4] = {b4.x, b4.y, b4.z, b4.w};
#pragma unroll
      for (int i = 0; i < 4; ++i)
#pragma unroll
        for (int j = 0; j < 4; ++j) acc[i][j] = fmaf(av[i], bv[j], acc[i][j]);
    }
    __syncthreads();
  }

#pragma unroll
  for (int i = 0; i < 4; ++i) {
    const size_t row = (size_t)(row0 + tr + i);
    float4 r4 = *reinterpret_cast<const float4*>(&Q[row * D + col0 + tc]);
    float4 o = make_float4(acc[i][0] + r4.x, acc[i][1] + r4.y,
                           acc[i][2] + r4.z, acc[i][3] + r4.w);
    *reinterpret_cast<float4*>(&XB[row * D + col0 + tc]) = o;
  }
}

// ---------------------------------------------------------------------------
// K6: LayerNorm per row of xb [M][D] -> out.
// grid: (M), block 256; 2 elements per thread.
// ---------------------------------------------------------------------------
__global__ __launch_bounds__(256) void ln_kernel(
    const float* __restrict__ XB, const float* __restrict__ gamma,
    const float* __restrict__ beta, float* __restrict__ OUT) {
  __shared__ float redS[4];
  __shared__ float redQ[4];
  const size_t row = blockIdx.x;
  const int tid = threadIdx.x;
  const float* x = XB + row * (size_t)D;

  float2 v = *reinterpret_cast<const float2*>(&x[tid * 2]);
  float s = v.x + v.y;
  s = wave_red_sum(s);
  if ((tid & 63) == 0) redS[tid >> 6] = s;
  __syncthreads();
  const float mu = (redS[0] + redS[1] + redS[2] + redS[3]) * (1.0f / D);

  float dx = v.x - mu, dy = v.y - mu;
  float q = dx * dx + dy * dy;
  q = wave_red_sum(q);
  if ((tid & 63) == 0) redQ[tid >> 6] = q;
  __syncthreads();
  const float var = (redQ[0] + redQ[1] + redQ[2] + redQ[3]) * (1.0f / D);
  const float rstd = rsqrtf(var + LN_EPS);

  float2 g = *reinterpret_cast<const float2*>(&gamma[tid * 2]);
  float2 bb = *reinterpret_cast<const float2*>(&beta[tid * 2]);
  float2 o;
  o.x = dx * rstd * g.x + bb.x;
  o.y = dy * rstd * g.y + bb.y;
  *reinterpret_cast<float2*>(&OUT[row * (size_t)D + tid * 2]) = o;
}

// ---------------------------------------------------------------------------
extern "C" void kernel_launch(void* const* d_in, const int* in_sizes, int n_in,
                              void* d_out, int out_size, void* d_ws,
                              size_t ws_size, hipStream_t stream) {
  const float* q     = (const float*)d_in[0];
  const float* k     = (const float*)d_in[1];
  const float* v     = (const float*)d_in[2];
  const float* w_q   = (const float*)d_in[3];
  const float* w_k   = (const float*)d_in[4];
  const float* w_v   = (const float*)d_in[5];
  const float* w_fc  = (const float*)d_in[6];
  const float* gamma = (const float*)d_in[7];
  const float* beta  = (const float*)d_in[8];

  float* out  = (float*)d_out;                 // [B,N,D]
  float* attn = out + (size_t)M * D;           // [B,H,N,N]

  float* ws = (float*)d_ws;                    // needs 48 MB
  float* qp = ws;                              // [B,H,N,DK]
  float* kp = ws + (size_t)M * D;
  float* vp = ws + 2 * (size_t)M * D;
  float* feat = qp;                            // reuse after scores
  float* xb   = kp;                            // reuse after pv

  dim3 blk(256);
  proj_kernel<<<dim3(M / 64, H), blk, 0, stream>>>(q, w_q, qp);
  proj_kernel<<<dim3(M / 64, H), blk, 0, stream>>>(k, w_k, kp);
  proj_kernel<<<dim3(M / 64, H), blk, 0, stream>>>(v, w_v, vp);
  scores_kernel<<<dim3(N / 64, N / 64, B * H), blk, 0, stream>>>(kp, qp, attn);
  softmax_kernel<<<dim3(B * H * N), blk, 0, stream>>>(attn);
  pv_kernel<<<dim3(N / 64, B * H), blk, 0, stream>>>(attn, vp, feat);
  fc_kernel<<<dim3(M / 64, D / 64), blk, 0, stream>>>(feat, w_fc, q, xb);
  ln_kernel<<<dim3(M), blk, 0, stream>>>(xb, gamma, beta, out);
}